// Round 4
// baseline (376.246 us; speedup 1.0000x reference)
//
#include <hip/hip_runtime.h>

// SceneSAGE: 3-layer GraphSAGE (mean agg) + ReLU + LayerNorm.
// N=40000 nodes, E=640000 edges, D: 128 -> 128 -> 64.
//
// Round 4: fused gather+MFMA layer kernel (mean gathered straight into
// A-fragment registers; no mean buffer round-trip), 8 dispatches total,
// single-block scan, fused prep kernel. Activations: NN x 128 bf16.

#define NN 40000
#define NE 640000
#define DH 128
#define LN_EPS 1e-5f

typedef __attribute__((ext_vector_type(8))) short short8;
typedef __attribute__((ext_vector_type(4))) float float4v;

__device__ __forceinline__ unsigned short f2b(float f) {
    unsigned int u = __float_as_uint(f);
    unsigned int r = (u + 0x7fffu + ((u >> 16) & 1u)) >> 16;
    return (unsigned short)r;
}
__device__ __forceinline__ float b2f(unsigned short b) {
    return __uint_as_float(((unsigned int)b) << 16);
}
__device__ __forceinline__ void acc8(float* a, short8 v) {
#pragma unroll
    for (int j = 0; j < 8; ++j)
        a[j] += __uint_as_float(((unsigned int)(unsigned short)v[j]) << 16);
}

// ---------------- CSR build ----------------

__global__ void hist_kernel(const int* __restrict__ dst, int* __restrict__ deg) {
    int i = blockIdx.x * blockDim.x + threadIdx.x;
    if (i < NE) atomicAdd(&deg[dst[i]], 1);
}

// single-block scan of 40000 degrees -> offs[0..NN], cursor[0..NN-1]
__global__ __launch_bounds__(1024) void scan_all(const int* __restrict__ deg,
                                                 int* __restrict__ offs,
                                                 int* __restrict__ cursor) {
    __shared__ int part[1024];
    const int C = 40;  // 1024*40 = 40960 >= NN
    int t = threadIdx.x;
    int base = t * C;
    int s = 0;
    for (int i = 0; i < C; ++i) {
        int idx = base + i;
        if (idx < NN) s += deg[idx];
    }
    part[t] = s;
    __syncthreads();
    for (int off = 1; off < 1024; off <<= 1) {
        int v = (t >= off) ? part[t - off] : 0;
        __syncthreads();
        part[t] += v;
        __syncthreads();
    }
    int run = (t > 0) ? part[t - 1] : 0;
    if (t == 0) { offs[0] = 0; cursor[0] = 0; }
    for (int i = 0; i < C; ++i) {
        int idx = base + i;
        if (idx < NN) {
            run += deg[idx];
            offs[idx + 1] = run;
            if (idx + 1 < NN) cursor[idx + 1] = run;
        }
    }
}

__global__ void scatter_edges(const int* __restrict__ src, const int* __restrict__ dst,
                              int* __restrict__ cursor, int* __restrict__ col) {
    int i = blockIdx.x * blockDim.x + threadIdx.x;
    if (i < NE) {
        int p = atomicAdd(&cursor[dst[i]], 1);
        col[p] = src[i];
    }
}

// ---------------- fused prep: convert x -> bf16 h, pack 3 weight sets ----
// Bp[ks][n][kk] = Wcat[ks*32+kk][n], Wcat = [Wl ; Wr] (256 x DC), bf16.

__device__ __forceinline__ void pack_one(const float* Wl, const float* Wr,
                                         unsigned short* Bp, int tid, int DC) {
    int k = tid / DC, n = tid % DC;
    float v = (k < 128) ? Wl[k * DC + n] : Wr[(k - 128) * DC + n];
    int ks = k >> 5, kk = k & 31;
    Bp[((size_t)ks * DC + n) * 32 + kk] = f2b(v);
}

__global__ __launch_bounds__(256) void prep_kernel(
    const float* __restrict__ x, unsigned short* __restrict__ h,
    const float* __restrict__ Wl0, const float* __restrict__ Wr0,
    const float* __restrict__ Wl1, const float* __restrict__ Wr1,
    const float* __restrict__ Wl2, const float* __restrict__ Wr2,
    unsigned short* __restrict__ W0p, unsigned short* __restrict__ W1p,
    unsigned short* __restrict__ W2p) {
    int b = blockIdx.x;
    if (b < 5000) {  // convert: 5000 blocks * 256 thr * 4 floats = 5.12M
        int idx = (b * 256 + threadIdx.x) * 4;
        float4 v = *(const float4*)(x + idx);
        unsigned int lo = (unsigned int)f2b(v.x) | ((unsigned int)f2b(v.y) << 16);
        unsigned int hi = (unsigned int)f2b(v.z) | ((unsigned int)f2b(v.w) << 16);
        unsigned int* p = (unsigned int*)(h + idx);
        p[0] = lo; p[1] = hi;
    } else if (b < 5128) {       // W0: 128 blocks
        pack_one(Wl0, Wr0, W0p, (b - 5000) * 256 + threadIdx.x, 128);
    } else if (b < 5256) {       // W1: 128 blocks
        pack_one(Wl1, Wr1, W1p, (b - 5128) * 256 + threadIdx.x, 128);
    } else {                     // W2: 64 blocks
        pack_one(Wl2, Wr2, W2p, (b - 5256) * 256 + threadIdx.x, 64);
    }
}

// ---------------- fused layer: gather-mean + dual MFMA GEMM + epilogue ----
// hin: NN x 128 bf16 rows. Block = 256 thr = 4 waves; wave = one 16-row
// M-tile; 625 blocks x 64 rows = 40000 exactly.
// Lane roles (gather + A-frags): l16 = row-in-tile, quad = k-octet.
// K = 256: steps 0..3 = mean (gathered in regs), 4..7 = self (global).

template <int DC, bool LNRELU>
__global__ __launch_bounds__(256) void layer_fused(
    const unsigned short* __restrict__ hin,
    const int* __restrict__ offs, const int* __restrict__ col,
    const unsigned short* __restrict__ Bp,
    const float* __restrict__ bl,
    const float* __restrict__ g, const float* __restrict__ bln,
    unsigned short* __restrict__ hout,   // LNRELU: next activations
    float* __restrict__ outf) {          // !LNRELU: final fp32 out
    constexpr int NT = DC / 16;
    const int tid = threadIdx.x;
    const int wave = tid >> 6, lane = tid & 63;
    const int quad = lane >> 4, l16 = lane & 15;
    const int row0 = blockIdx.x * 64 + wave * 16;   // tile base
    const int myrow = row0 + l16;                   // this lane's gather row

    // ---- gather mean into A-fragment-layout registers ----
    float accm[4][8];
#pragma unroll
    for (int k = 0; k < 4; ++k)
#pragma unroll
        for (int j = 0; j < 8; ++j) accm[k][j] = 0.f;

    const int beg = offs[myrow], end = offs[myrow + 1];
    const unsigned short* hq = hin + quad * 8;
    int e = beg;
    for (; e + 1 < end; e += 2) {
        int c0 = col[e], c1 = col[e + 1];
        const unsigned short* r0 = hq + (size_t)c0 * 128;
        const unsigned short* r1 = hq + (size_t)c1 * 128;
        short8 u0 = *(const short8*)(r0);
        short8 u1 = *(const short8*)(r0 + 32);
        short8 u2 = *(const short8*)(r0 + 64);
        short8 u3 = *(const short8*)(r0 + 96);
        short8 w0 = *(const short8*)(r1);
        short8 w1 = *(const short8*)(r1 + 32);
        short8 w2 = *(const short8*)(r1 + 64);
        short8 w3 = *(const short8*)(r1 + 96);
        acc8(accm[0], u0); acc8(accm[1], u1);
        acc8(accm[2], u2); acc8(accm[3], u3);
        acc8(accm[0], w0); acc8(accm[1], w1);
        acc8(accm[2], w2); acc8(accm[3], w3);
    }
    if (e < end) {
        int c = col[e];
        const unsigned short* r0 = hq + (size_t)c * 128;
        short8 u0 = *(const short8*)(r0);
        short8 u1 = *(const short8*)(r0 + 32);
        short8 u2 = *(const short8*)(r0 + 64);
        short8 u3 = *(const short8*)(r0 + 96);
        acc8(accm[0], u0); acc8(accm[1], u1);
        acc8(accm[2], u2); acc8(accm[3], u3);
    }

    const float inv = 1.0f / fmaxf((float)(end - beg), 1.0f);
    short8 am[4];
#pragma unroll
    for (int k = 0; k < 4; ++k)
#pragma unroll
        for (int j = 0; j < 8; ++j) am[k][j] = (short)f2b(accm[k][j] * inv);

    // ---- self A-fragments (direct from global) ----
    const unsigned short* sp = hin + (size_t)myrow * 128 + quad * 8;
    short8 as[4];
    as[0] = *(const short8*)(sp);
    as[1] = *(const short8*)(sp + 32);
    as[2] = *(const short8*)(sp + 64);
    as[3] = *(const short8*)(sp + 96);

    // ---- MFMA K-loop ----
    float4v acc[NT];
#pragma unroll
    for (int nt = 0; nt < NT; ++nt)
#pragma unroll
        for (int r = 0; r < 4; ++r) acc[nt][r] = 0.f;

#pragma unroll
    for (int ks = 0; ks < 8; ++ks) {
        short8 a = (ks < 4) ? am[ks] : as[ks - 4];
        const unsigned short* bp = Bp + ((size_t)ks * DC + l16) * 32 + quad * 8;
#pragma unroll
        for (int nt = 0; nt < NT; ++nt) {
            short8 b = *(const short8*)(bp + nt * 16 * 32);
            acc[nt] = __builtin_amdgcn_mfma_f32_16x16x32_bf16(a, b, acc[nt], 0, 0, 0);
        }
    }

    // ---- epilogue (C-layout: out row = row0 + quad*4 + r, col = nt*16+l16) --
    float bias[NT];
#pragma unroll
    for (int nt = 0; nt < NT; ++nt) bias[nt] = bl[nt * 16 + l16];

    if (!LNRELU) {
#pragma unroll
        for (int r = 0; r < 4; ++r) {
            long orow = row0 + quad * 4 + r;
#pragma unroll
            for (int nt = 0; nt < NT; ++nt)
                outf[orow * DC + nt * 16 + l16] = acc[nt][r] + bias[nt];
        }
    } else {
        float gv[NT], bv[NT];
#pragma unroll
        for (int nt = 0; nt < NT; ++nt) { gv[nt] = g[nt * 16 + l16]; bv[nt] = bln[nt * 16 + l16]; }
#pragma unroll
        for (int r = 0; r < 4; ++r) {
            float v[NT];
            float s = 0.f, q = 0.f;
#pragma unroll
            for (int nt = 0; nt < NT; ++nt) {
                float t = fmaxf(acc[nt][r] + bias[nt], 0.f);
                v[nt] = t; s += t; q += t * t;
            }
#pragma unroll
            for (int mask = 1; mask < 16; mask <<= 1) {
                s += __shfl_xor(s, mask, 64);
                q += __shfl_xor(q, mask, 64);
            }
            float mu = s * (1.f / 128.f);
            float rstd = rsqrtf(q * (1.f / 128.f) - mu * mu + LN_EPS);
            long orow = row0 + quad * 4 + r;
            unsigned short* op = hout + orow * 128 + l16;
#pragma unroll
            for (int nt = 0; nt < NT; ++nt)
                op[nt * 16] = f2b((v[nt] - mu) * rstd * gv[nt] + bv[nt]);
        }
    }
}

// ---------------- launch ----------------

static inline size_t alignup(size_t x) { return (x + 1023) & ~(size_t)1023; }

extern "C" void kernel_launch(void* const* d_in, const int* in_sizes, int n_in,
                              void* d_out, int out_size, void* d_ws, size_t ws_size,
                              hipStream_t stream) {
    const float* x   = (const float*)d_in[0];
    const int* ei    = (const int*)d_in[1];
    const float* Wl0 = (const float*)d_in[2];
    const float* bl0 = (const float*)d_in[3];
    const float* Wr0 = (const float*)d_in[4];
    const float* Wl1 = (const float*)d_in[5];
    const float* bl1 = (const float*)d_in[6];
    const float* Wr1 = (const float*)d_in[7];
    const float* Wl2 = (const float*)d_in[8];
    const float* bl2 = (const float*)d_in[9];
    const float* Wr2 = (const float*)d_in[10];
    const float* g0  = (const float*)d_in[11];
    const float* b0  = (const float*)d_in[12];
    const float* g1  = (const float*)d_in[13];
    const float* b1  = (const float*)d_in[14];

    const int* src = ei;
    const int* dst = ei + NE;

    char* p = (char*)d_ws;
    int* deg    = (int*)p; p += alignup((size_t)NN * 4);
    int* offs   = (int*)p; p += alignup((size_t)(NN + 1) * 4);
    int* cursor = (int*)p; p += alignup((size_t)NN * 4);
    int* col    = (int*)p; p += alignup((size_t)NE * 4);
    unsigned short* hA = (unsigned short*)p; p += alignup((size_t)NN * 128 * 2);
    unsigned short* hB = (unsigned short*)p; p += alignup((size_t)NN * 128 * 2);
    unsigned short* W0p = (unsigned short*)p; p += alignup((size_t)256 * 128 * 2);
    unsigned short* W1p = (unsigned short*)p; p += alignup((size_t)256 * 128 * 2);
    unsigned short* W2p = (unsigned short*)p; p += alignup((size_t)256 * 64 * 2);
    float* outf = (float*)d_out;

    // ---- CSR build (4 dispatches incl. memset) ----
    hipMemsetAsync(deg, 0, (size_t)NN * 4, stream);
    hist_kernel<<<(NE + 255) / 256, 256, 0, stream>>>(dst, deg);
    scan_all<<<1, 1024, 0, stream>>>(deg, offs, cursor);
    scatter_edges<<<(NE + 255) / 256, 256, 0, stream>>>(src, dst, cursor, col);

    // ---- prep: convert x + pack all weights (1 dispatch) ----
    prep_kernel<<<5320, 256, 0, stream>>>(x, hA, Wl0, Wr0, Wl1, Wr1, Wl2, Wr2,
                                          W0p, W1p, W2p);

    const int layerBlocks = NN / 64;   // 625

    // ---- 3 fused layers ----
    layer_fused<128, true><<<layerBlocks, 256, 0, stream>>>(
        hA, offs, col, W0p, bl0, g0, b0, hB, nullptr);
    layer_fused<128, true><<<layerBlocks, 256, 0, stream>>>(
        hB, offs, col, W1p, bl1, g1, b1, hA, nullptr);
    layer_fused<64, false><<<layerBlocks, 256, 0, stream>>>(
        hA, offs, col, W2p, bl2, nullptr, nullptr, nullptr, outf);
}

// Round 5
// 277.776 us; speedup vs baseline: 1.3545x; 1.3545x over previous
//
#include <hip/hip_runtime.h>

// SceneSAGE: 3-layer GraphSAGE (mean agg) + ReLU + LayerNorm.
// N=40000 nodes, E=640000 edges, D: 128 -> 128 -> 64.
//
// Round 5: parallel 3-stage scan restored (round-4's single-block scan_all
// was 97 us on one CU); layer kernel = 1 wave / 16-row M-tile, 2500 blocks
// (even CU balance); hist+prep fused; self-row prefetched before gather.

#define NN 40000
#define NE 640000
#define DH 128
#define LN_EPS 1e-5f

typedef __attribute__((ext_vector_type(8))) short short8;
typedef __attribute__((ext_vector_type(4))) float float4v;

__device__ __forceinline__ unsigned short f2b(float f) {
    unsigned int u = __float_as_uint(f);
    unsigned int r = (u + 0x7fffu + ((u >> 16) & 1u)) >> 16;
    return (unsigned short)r;
}
__device__ __forceinline__ void acc8(float* a, short8 v) {
#pragma unroll
    for (int j = 0; j < 8; ++j)
        a[j] += __uint_as_float(((unsigned int)(unsigned short)v[j]) << 16);
}

// ---------------- combined hist + prep (independent work) ----------------
// blocks [0,2500): histogram of dst. blocks [2500,7820): convert x / pack W.

__device__ __forceinline__ void pack_one(const float* Wl, const float* Wr,
                                         unsigned short* Bp, int tid, int DC) {
    int k = tid / DC, n = tid % DC;
    float v = (k < 128) ? Wl[k * DC + n] : Wr[(k - 128) * DC + n];
    int ks = k >> 5, kk = k & 31;
    Bp[((size_t)ks * DC + n) * 32 + kk] = f2b(v);
}

__global__ __launch_bounds__(256) void hist_prep_kernel(
    const int* __restrict__ dst, int* __restrict__ deg,
    const float* __restrict__ x, unsigned short* __restrict__ h,
    const float* __restrict__ Wl0, const float* __restrict__ Wr0,
    const float* __restrict__ Wl1, const float* __restrict__ Wr1,
    const float* __restrict__ Wl2, const float* __restrict__ Wr2,
    unsigned short* __restrict__ W0p, unsigned short* __restrict__ W1p,
    unsigned short* __restrict__ W2p) {
    int b = blockIdx.x;
    if (b < 2500) {                       // histogram: 2500*256 = 640000
        int i = b * 256 + threadIdx.x;
        atomicAdd(&deg[dst[i]], 1);
    } else if (b < 7500) {                // convert: 5000 blocks * 1024 floats
        int idx = ((b - 2500) * 256 + threadIdx.x) * 4;
        float4 v = *(const float4*)(x + idx);
        unsigned int lo = (unsigned int)f2b(v.x) | ((unsigned int)f2b(v.y) << 16);
        unsigned int hi = (unsigned int)f2b(v.z) | ((unsigned int)f2b(v.w) << 16);
        unsigned int* p = (unsigned int*)(h + idx);
        p[0] = lo; p[1] = hi;
    } else if (b < 7628) {                // W0: 128 blocks
        pack_one(Wl0, Wr0, W0p, (b - 7500) * 256 + threadIdx.x, 128);
    } else if (b < 7756) {                // W1: 128 blocks
        pack_one(Wl1, Wr1, W1p, (b - 7628) * 256 + threadIdx.x, 128);
    } else {                              // W2: 64 blocks
        pack_one(Wl2, Wr2, W2p, (b - 7756) * 256 + threadIdx.x, 64);
    }
}

// ---------------- 3-stage parallel scan ----------------

__global__ void scan_block(const int* __restrict__ deg, int* __restrict__ offs,
                           int* __restrict__ bsums) {
    __shared__ int s[256];
    int i = blockIdx.x * 256 + threadIdx.x;
    int v = (i < NN) ? deg[i] : 0;
    s[threadIdx.x] = v;
    __syncthreads();
    for (int off = 1; off < 256; off <<= 1) {
        int t = (threadIdx.x >= off) ? s[threadIdx.x - off] : 0;
        __syncthreads();
        s[threadIdx.x] += t;
        __syncthreads();
    }
    if (i < NN) offs[i + 1] = s[threadIdx.x];
    if (threadIdx.x == 255) bsums[blockIdx.x] = s[255];
}

// exclusive scan of bsums (nb <= 256) in one 256-thread block
__global__ void scan_sums(int* __restrict__ bsums, int nb) {
    __shared__ int s[256];
    int t = threadIdx.x;
    int v = (t < nb) ? bsums[t] : 0;
    s[t] = v;
    __syncthreads();
    for (int off = 1; off < 256; off <<= 1) {
        int u = (t >= off) ? s[t - off] : 0;
        __syncthreads();
        s[t] += u;
        __syncthreads();
    }
    if (t < nb) bsums[t] = s[t] - v;
}

// offs[i+1] += bsums[block]; cursor[i] = final offs[i].
__global__ void add_offs(int* __restrict__ offs, const int* __restrict__ bsums,
                         int* __restrict__ cursor) {
    int i = blockIdx.x * blockDim.x + threadIdx.x;
    if (i == 0) { offs[0] = 0; cursor[0] = 0; }
    if (i < NN) {
        int o = offs[i + 1] + bsums[i >> 8];
        offs[i + 1] = o;
        if (i + 1 < NN) cursor[i + 1] = o;
    }
}

__global__ void scatter_edges(const int* __restrict__ src, const int* __restrict__ dst,
                              int* __restrict__ cursor, int* __restrict__ col) {
    int i = blockIdx.x * blockDim.x + threadIdx.x;
    if (i < NE) {
        int p = atomicAdd(&cursor[dst[i]], 1);
        col[p] = src[i];
    }
}

// ---------------- fused layer: gather-mean + dual MFMA GEMM + epilogue ----
// hin: NN x 128 bf16 rows. Block = 64 thr = 1 wave = one 16-row M-tile.
// 2500 blocks x 16 rows = 40000 exactly.
// Lane roles: l16 = row-in-tile, quad = k-octet (16B piece of the row).
// K = 256: steps 0..3 = mean (gathered in regs), 4..7 = self.

template <int DC, bool LNRELU>
__global__ __launch_bounds__(64) void layer_fused(
    const unsigned short* __restrict__ hin,
    const int* __restrict__ offs, const int* __restrict__ col,
    const unsigned short* __restrict__ Bp,
    const float* __restrict__ bl,
    const float* __restrict__ g, const float* __restrict__ bln,
    unsigned short* __restrict__ hout,   // LNRELU: next activations
    float* __restrict__ outf) {          // !LNRELU: final fp32 out
    constexpr int NT = DC / 16;
    const int lane = threadIdx.x;
    const int quad = lane >> 4, l16 = lane & 15;
    const int row0 = blockIdx.x * 16;
    const int myrow = row0 + l16;

    // ---- prefetch self A-fragments (independent of gather) ----
    const unsigned short* sp = hin + (size_t)myrow * 128 + quad * 8;
    short8 as0 = *(const short8*)(sp);
    short8 as1 = *(const short8*)(sp + 32);
    short8 as2 = *(const short8*)(sp + 64);
    short8 as3 = *(const short8*)(sp + 96);

    // ---- gather mean into A-fragment-layout registers ----
    float accm[4][8];
#pragma unroll
    for (int k = 0; k < 4; ++k)
#pragma unroll
        for (int j = 0; j < 8; ++j) accm[k][j] = 0.f;

    const int beg = offs[myrow], end = offs[myrow + 1];
    const unsigned short* hq = hin + quad * 8;
    int e = beg;
    for (; e + 1 < end; e += 2) {
        int c0 = col[e], c1 = col[e + 1];
        const unsigned short* r0 = hq + (size_t)c0 * 128;
        const unsigned short* r1 = hq + (size_t)c1 * 128;
        short8 u0 = *(const short8*)(r0);
        short8 u1 = *(const short8*)(r0 + 32);
        short8 u2 = *(const short8*)(r0 + 64);
        short8 u3 = *(const short8*)(r0 + 96);
        short8 w0 = *(const short8*)(r1);
        short8 w1 = *(const short8*)(r1 + 32);
        short8 w2 = *(const short8*)(r1 + 64);
        short8 w3 = *(const short8*)(r1 + 96);
        acc8(accm[0], u0); acc8(accm[1], u1);
        acc8(accm[2], u2); acc8(accm[3], u3);
        acc8(accm[0], w0); acc8(accm[1], w1);
        acc8(accm[2], w2); acc8(accm[3], w3);
    }
    if (e < end) {
        int c = col[e];
        const unsigned short* r0 = hq + (size_t)c * 128;
        short8 u0 = *(const short8*)(r0);
        short8 u1 = *(const short8*)(r0 + 32);
        short8 u2 = *(const short8*)(r0 + 64);
        short8 u3 = *(const short8*)(r0 + 96);
        acc8(accm[0], u0); acc8(accm[1], u1);
        acc8(accm[2], u2); acc8(accm[3], u3);
    }

    const float inv = 1.0f / fmaxf((float)(end - beg), 1.0f);
    short8 am[4];
#pragma unroll
    for (int k = 0; k < 4; ++k)
#pragma unroll
        for (int j = 0; j < 8; ++j) am[k][j] = (short)f2b(accm[k][j] * inv);

    // ---- MFMA K-loop ----
    float4v acc[NT];
#pragma unroll
    for (int nt = 0; nt < NT; ++nt)
#pragma unroll
        for (int r = 0; r < 4; ++r) acc[nt][r] = 0.f;

    short8 as[4] = {as0, as1, as2, as3};
#pragma unroll
    for (int ks = 0; ks < 8; ++ks) {
        short8 a = (ks < 4) ? am[ks] : as[ks - 4];
        const unsigned short* bp = Bp + ((size_t)ks * DC + l16) * 32 + quad * 8;
#pragma unroll
        for (int nt = 0; nt < NT; ++nt) {
            short8 b = *(const short8*)(bp + nt * 16 * 32);
            acc[nt] = __builtin_amdgcn_mfma_f32_16x16x32_bf16(a, b, acc[nt], 0, 0, 0);
        }
    }

    // ---- epilogue (C-layout: row = row0 + quad*4 + r, col = nt*16 + l16) ----
    float bias[NT];
#pragma unroll
    for (int nt = 0; nt < NT; ++nt) bias[nt] = bl[nt * 16 + l16];

    if (!LNRELU) {
#pragma unroll
        for (int r = 0; r < 4; ++r) {
            long orow = row0 + quad * 4 + r;
#pragma unroll
            for (int nt = 0; nt < NT; ++nt)
                outf[orow * DC + nt * 16 + l16] = acc[nt][r] + bias[nt];
        }
    } else {
        float gv[NT], bv[NT];
#pragma unroll
        for (int nt = 0; nt < NT; ++nt) { gv[nt] = g[nt * 16 + l16]; bv[nt] = bln[nt * 16 + l16]; }
#pragma unroll
        for (int r = 0; r < 4; ++r) {
            float v[NT];
            float s = 0.f, q = 0.f;
#pragma unroll
            for (int nt = 0; nt < NT; ++nt) {
                float t = fmaxf(acc[nt][r] + bias[nt], 0.f);
                v[nt] = t; s += t; q += t * t;
            }
#pragma unroll
            for (int mask = 1; mask < 16; mask <<= 1) {
                s += __shfl_xor(s, mask, 64);
                q += __shfl_xor(q, mask, 64);
            }
            float mu = s * (1.f / 128.f);
            float rstd = rsqrtf(q * (1.f / 128.f) - mu * mu + LN_EPS);
            long orow = row0 + quad * 4 + r;
            unsigned short* op = hout + orow * 128 + l16;
#pragma unroll
            for (int nt = 0; nt < NT; ++nt)
                op[nt * 16] = f2b((v[nt] - mu) * rstd * gv[nt] + bv[nt]);
        }
    }
}

// ---------------- launch ----------------

static inline size_t alignup(size_t x) { return (x + 1023) & ~(size_t)1023; }

extern "C" void kernel_launch(void* const* d_in, const int* in_sizes, int n_in,
                              void* d_out, int out_size, void* d_ws, size_t ws_size,
                              hipStream_t stream) {
    const float* x   = (const float*)d_in[0];
    const int* ei    = (const int*)d_in[1];
    const float* Wl0 = (const float*)d_in[2];
    const float* bl0 = (const float*)d_in[3];
    const float* Wr0 = (const float*)d_in[4];
    const float* Wl1 = (const float*)d_in[5];
    const float* bl1 = (const float*)d_in[6];
    const float* Wr1 = (const float*)d_in[7];
    const float* Wl2 = (const float*)d_in[8];
    const float* bl2 = (const float*)d_in[9];
    const float* Wr2 = (const float*)d_in[10];
    const float* g0  = (const float*)d_in[11];
    const float* b0  = (const float*)d_in[12];
    const float* g1  = (const float*)d_in[13];
    const float* b1  = (const float*)d_in[14];

    const int* src = ei;
    const int* dst = ei + NE;

    char* p = (char*)d_ws;
    int* deg    = (int*)p; p += alignup((size_t)NN * 4);
    int* offs   = (int*)p; p += alignup((size_t)(NN + 1) * 4);
    int* bsums  = (int*)p; p += alignup(256 * 4);
    int* cursor = (int*)p; p += alignup((size_t)NN * 4);
    int* col    = (int*)p; p += alignup((size_t)NE * 4);
    unsigned short* hA = (unsigned short*)p; p += alignup((size_t)NN * 128 * 2);
    unsigned short* hB = (unsigned short*)p; p += alignup((size_t)NN * 128 * 2);
    unsigned short* W0p = (unsigned short*)p; p += alignup((size_t)256 * 128 * 2);
    unsigned short* W1p = (unsigned short*)p; p += alignup((size_t)256 * 128 * 2);
    unsigned short* W2p = (unsigned short*)p; p += alignup((size_t)256 * 64 * 2);
    float* outf = (float*)d_out;

    const int nbScan = (NN + 255) / 256;   // 157

    // ---- memset + combined hist/convert/pack ----
    hipMemsetAsync(deg, 0, (size_t)NN * 4, stream);
    hist_prep_kernel<<<7820, 256, 0, stream>>>(dst, deg, x, hA,
                                               Wl0, Wr0, Wl1, Wr1, Wl2, Wr2,
                                               W0p, W1p, W2p);

    // ---- scan + scatter ----
    scan_block<<<nbScan, 256, 0, stream>>>(deg, offs, bsums);
    scan_sums<<<1, 256, 0, stream>>>(bsums, nbScan);
    add_offs<<<nbScan, 256, 0, stream>>>(offs, bsums, cursor);
    scatter_edges<<<(NE + 255) / 256, 256, 0, stream>>>(src, dst, cursor, col);

    const int layerBlocks = NN / 16;   // 2500

    // ---- 3 fused layers ----
    layer_fused<128, true><<<layerBlocks, 64, 0, stream>>>(
        hA, offs, col, W0p, bl0, g0, b0, hB, nullptr);
    layer_fused<128, true><<<layerBlocks, 64, 0, stream>>>(
        hB, offs, col, W1p, bl1, g1, b1, hA, nullptr);
    layer_fused<64, false><<<layerBlocks, 64, 0, stream>>>(
        hA, offs, col, W2p, bl2, nullptr, nullptr, nullptr, outf);
}